// Round 6
// baseline (204.132 us; speedup 1.0000x reference)
//
#include <hip/hip_runtime.h>
#include <hip/hip_bf16.h>

typedef unsigned int u32;
typedef unsigned char u8;
typedef _Float16 f16;
typedef f16 f16x2 __attribute__((ext_vector_type(2)));
typedef short s16x8 __attribute__((ext_vector_type(8)));
typedef float f32x4 __attribute__((ext_vector_type(4)));

#define BB 64
#define LL 128
#define TT 64
#define NN 128
#define NM (NN*NN)   // 16384

__device__ __forceinline__ float sigf(float v) {
    return 1.0f / (1.0f + __expf(-v));
}

__device__ __forceinline__ float clip01(float v) {
    return fminf(fmaxf(v, 0.f), 1.f);
}

__device__ __forceinline__ u32 f2bf(float f) {   // f32 -> bf16 bits (RNE)
    u32 u = __builtin_bit_cast(u32, f);
    return (u + 0x7fffu + ((u >> 16) & 1u)) >> 16;
}

__device__ __forceinline__ float fdot2f(f16x2 wa, f16x2 xa, float ca) {
#if defined(__HIP_DEVICE_COMPILE__) && __has_builtin(__builtin_amdgcn_fdot2)
    return __builtin_amdgcn_fdot2(wa, xa, ca, false);
#else
    return ca + (float)wa[0] * (float)xa[0] + (float)wa[1] * (float)xa[1];
#endif
}

// ---------------------------------------------------------------------------
// pack_w: sigmoid(ntp) -> bf16 A-fragment order for mfma_f32_16x16x32_bf16.
// A-tile (i, khalf h): lane l holds A[row=l&15][k = h*32 + (l>>4)*8 + e], e=0..7.
__global__ __launch_bounds__(256) void pack_w(const float* __restrict__ ntp,
                                              ushort* __restrict__ wpk) {
    const int g = blockIdx.x * 256 + threadIdx.x;   // 0..131071
    const int l = g & 63, h = (g >> 6) & 1, i = g >> 7;
    const int row = i * 16 + (l & 15);
    const int t0 = h * 32 + ((l >> 4) << 3);
    const float* src = ntp + row * 64 + t0;
    float4 f0 = *reinterpret_cast<const float4*>(src);
    float4 f1 = *reinterpret_cast<const float4*>(src + 4);
    float v[8] = {f0.x, f0.y, f0.z, f0.w, f1.x, f1.y, f1.z, f1.w};
    u32 o[4];
    #pragma unroll
    for (int q = 0; q < 4; ++q)
        o[q] = f2bf(sigf(v[2 * q])) | (f2bf(sigf(v[2 * q + 1])) << 16);
    uint4 ov; ov.x = o[0]; ov.y = o[1]; ov.z = o[2]; ov.w = o[3];
    *reinterpret_cast<uint4*>(wpk + (size_t)g * 8) = ov;
}

// ---------------------------------------------------------------------------
// pack_x: x -> bf16 B-fragment order.
__global__ __launch_bounds__(256) void pack_x(const float* __restrict__ x_all,
                                              ushort* __restrict__ xpk) {
    const int g = blockIdx.x * 256 + threadIdx.x;   // 0..65535
    const int l = g & 63, h = (g >> 6) & 1, j = (g >> 7) & 7, b = g >> 10;
    const int s = j * 16 + (l & 15);
    const int t0 = h * 32 + ((l >> 4) << 3);
    const float* src = x_all + ((size_t)b * LL + s) * TT + t0;
    float4 f0 = *reinterpret_cast<const float4*>(src);
    float4 f1 = *reinterpret_cast<const float4*>(src + 4);
    float v[8] = {f0.x, f0.y, f0.z, f0.w, f1.x, f1.y, f1.z, f1.w};
    u32 o[4];
    #pragma unroll
    for (int q = 0; q < 4; ++q)
        o[q] = f2bf(v[2 * q]) | (f2bf(v[2 * q + 1]) << 16);
    uint4 ov; ov.x = o[0]; ov.y = o[1]; ov.z = o[2]; ov.w = o[3];
    *reinterpret_cast<uint4*>(xpk + (size_t)g * 8) = ov;
}

// ---------------------------------------------------------------------------
// gemm_mfma: npc in TILE layout: slab(b,i) = npc + (b*1024+i)*2048;
// within slab: byte offset s*16 + rq  (rq = nm within tile, 0..15), u8 value.
// Wave store pattern per (tile i, j): offsets j*256 + (l&15)*16 + (l>>4)*4
// -> one contiguous 256B block per store round: fully coalesced.
// Grid 1024 wgs = (b in 64) x (nb in 16); 4 waves; wave handles 16 nm-tiles.
__global__ __launch_bounds__(256) void gemm_mfma(const ushort* __restrict__ wpk,
                                                 const ushort* __restrict__ xpk,
                                                 u8* __restrict__ npc) {
    const int b = blockIdx.x >> 4;
    const int nb = blockIdx.x & 15;
    const int wv = threadIdx.x >> 6, l = threadIdx.x & 63;

    uint4 xf[8][2];
    #pragma unroll
    for (int j = 0; j < 8; ++j)
        #pragma unroll
        for (int h = 0; h < 2; ++h)
            xf[j][h] = *reinterpret_cast<const uint4*>(
                xpk + (size_t)(((b * 8 + j) * 2 + h) * 64 + l) * 8);

    const int c = l & 15, r0 = (l >> 4) * 4;

    for (int it = 0; it < 16; ++it) {
        const int i = nb * 64 + wv * 16 + it;        // nm-tile index 0..1023
        uint4 a0 = *reinterpret_cast<const uint4*>(wpk + (size_t)((i * 2 + 0) * 64 + l) * 8);
        uint4 a1 = *reinterpret_cast<const uint4*>(wpk + (size_t)((i * 2 + 1) * 64 + l) * 8);
        f32x4 acc[8];
        const f32x4 z = {0.f, 0.f, 0.f, 0.f};
        #pragma unroll
        for (int j = 0; j < 8; ++j)
            acc[j] = __builtin_amdgcn_mfma_f32_16x16x32_bf16(
                __builtin_bit_cast(s16x8, a0), __builtin_bit_cast(s16x8, xf[j][0]), z, 0, 0, 0);
        #pragma unroll
        for (int j = 0; j < 8; ++j)
            acc[j] = __builtin_amdgcn_mfma_f32_16x16x32_bf16(
                __builtin_bit_cast(s16x8, a1), __builtin_bit_cast(s16x8, xf[j][1]), acc[j], 0, 0, 0);

        u8* dst = npc + (((size_t)(b * 1024 + i)) << 11);   // 2048 B slab
        #pragma unroll
        for (int j = 0; j < 8; ++j) {
            u32 w = 0;
            #pragma unroll
            for (int r = 0; r < 4; ++r) {
                float q = clip01(acc[j][r]) * 255.f + 0.5f;
                w |= ((u32)q) << (8 * r);
            }
            *reinterpret_cast<u32*>(dst + ((j * 16 + c) << 4) + r0) = w;
        }
    }
}

// ---------------------------------------------------------------------------
// recur3: sequential recursion on tile-layout npc.
// Thread tid owns tile i = tid (16 m's: m = (tid&7)*16 + 0..15, n = tid>>3).
// Steps processed in blocks of 4: one 64B (4x uint4) full-line load per thread
// per block, 3-block register pipeline (modulo-3 unrolled, no reg rotation).
__global__ __launch_bounds__(1024) void recur3(const float* __restrict__ x_all,
                                               const float* __restrict__ tp,
                                               const u8* __restrict__ npc,
                                               float* __restrict__ outp) {
    __shared__ __align__(16) ushort prevh[2][NN];
    __shared__ float masks[LL];
    __shared__ float x0[TT];

    const int b = blockIdx.x, tid = threadIdx.x;
    if (tid < 128) masks[tid] = x_all[(size_t)b * 8192 + tid * 64 + 63];
    else if (tid < 192) x0[tid - 128] = x_all[(size_t)b * 8192 + (tid - 128)];
    __syncthreads();

    float out_r = 0.f;
    if (tid < 128) {
        float a = 0.f;
        #pragma unroll 8
        for (int t = 0; t < TT; ++t)
            a += sigf(tp[tid * TT + t]) * x0[t];
        f16 ha = (f16)a;
        prevh[0][tid] = __builtin_bit_cast(ushort, ha);
        if (tid == 0) out_r = a;               // out0 = tpc[0], exact fp32
    }
    __syncthreads();

    const int n = tid >> 3, sub = tid & 7;
    const char* pbase = reinterpret_cast<const char*>(&prevh[0][0]);
    const u8* base = npc + ((size_t)b << 21) + ((size_t)tid << 11);

    int p = 0;

#define LD4(D, KK) do { \
        const uint4* _q = reinterpret_cast<const uint4*>(base + (size_t)(KK) * 64); \
        D[0] = _q[0]; D[1] = _q[1]; D[2] = _q[2]; D[3] = _q[3]; } while (0)

#define STEP(CV, SS) do { \
        uint4 ph0 = *reinterpret_cast<const uint4*>(pbase + p * 256 + sub * 32); \
        uint4 ph1 = *reinterpret_cast<const uint4*>(pbase + p * 256 + sub * 32 + 16); \
        f16x2 a0 = __builtin_bit_cast(f16x2, ph0.x), a1 = __builtin_bit_cast(f16x2, ph0.y); \
        f16x2 a2 = __builtin_bit_cast(f16x2, ph0.z), a3 = __builtin_bit_cast(f16x2, ph0.w); \
        f16x2 a4 = __builtin_bit_cast(f16x2, ph1.x), a5 = __builtin_bit_cast(f16x2, ph1.y); \
        f16x2 a6 = __builtin_bit_cast(f16x2, ph1.z), a7 = __builtin_bit_cast(f16x2, ph1.w); \
        u32 w0 = (CV).x, w1 = (CV).y, w2 = (CV).z, w3 = (CV).w; \
        float s0 = 0.f, s1 = 0.f; \
        s0 = fmaf((float)(w0 & 255u), (float)a0[0], s0); \
        s1 = fmaf((float)((w0 >> 8) & 255u), (float)a0[1], s1); \
        s0 = fmaf((float)((w0 >> 16) & 255u), (float)a1[0], s0); \
        s1 = fmaf((float)(w0 >> 24), (float)a1[1], s1); \
        s0 = fmaf((float)(w1 & 255u), (float)a2[0], s0); \
        s1 = fmaf((float)((w1 >> 8) & 255u), (float)a2[1], s1); \
        s0 = fmaf((float)((w1 >> 16) & 255u), (float)a3[0], s0); \
        s1 = fmaf((float)(w1 >> 24), (float)a3[1], s1); \
        s0 = fmaf((float)(w2 & 255u), (float)a4[0], s0); \
        s1 = fmaf((float)((w2 >> 8) & 255u), (float)a4[1], s1); \
        s0 = fmaf((float)((w2 >> 16) & 255u), (float)a5[0], s0); \
        s1 = fmaf((float)(w2 >> 24), (float)a5[1], s1); \
        s0 = fmaf((float)(w3 & 255u), (float)a6[0], s0); \
        s1 = fmaf((float)((w3 >> 8) & 255u), (float)a6[1], s1); \
        s0 = fmaf((float)((w3 >> 16) & 255u), (float)a7[0], s0); \
        s1 = fmaf((float)(w3 >> 24), (float)a7[1], s1); \
        float sum = (s0 + s1) * (1.0f / 255.0f); \
        sum += __shfl_xor(sum, 1); \
        sum += __shfl_xor(sum, 2); \
        sum += __shfl_xor(sum, 4); \
        float cc = clip01(sum); \
        if (sub == 0) { \
            f16 hc = (f16)cc; \
            prevh[p ^ 1][n] = __builtin_bit_cast(ushort, hc); \
        } \
        if (tid == 0) { \
            float mk = masks[(SS)]; \
            out_r = out_r * mk + cc * (1.f - mk); \
        } \
        __builtin_amdgcn_sched_barrier(0); \
        asm volatile("s_waitcnt lgkmcnt(0)"); \
        __builtin_amdgcn_s_barrier(); \
        __builtin_amdgcn_sched_barrier(0); \
        p ^= 1; } while (0)

    uint4 bA[4], bB[4], bC[4];
    LD4(bA, 0); LD4(bB, 1); LD4(bC, 2);

    // block 0: steps 1..3 (block covers s=0..3; s=0 unused)
    STEP(bA[1], 1); STEP(bA[2], 2); STEP(bA[3], 3);
    LD4(bA, 3);

    // blocks kk=1..31, 3 at a time; block k covers steps 4k..4k+3 (<=127)
    for (int kk = 1; kk <= 28; kk += 3) {
        #pragma unroll
        for (int e = 0; e < 4; ++e) STEP(bB[e], 4 * kk + e);
        { int kn = kk + 4; if (kn > 31) kn = 31; LD4(bB, kn); }
        #pragma unroll
        for (int e = 0; e < 4; ++e) STEP(bC[e], 4 * (kk + 1) + e);
        { int kn = kk + 5; if (kn > 31) kn = 31; LD4(bC, kn); }
        #pragma unroll
        for (int e = 0; e < 4; ++e) STEP(bA[e], 4 * (kk + 2) + e);
        { int kn = kk + 6; if (kn > 31) kn = 31; LD4(bA, kn); }
    }
    // leftover block kk=31 (in bB: loaded as kn=31 at kk=28)
    #pragma unroll
    for (int e = 0; e < 4; ++e) STEP(bB[e], 124 + e);

#undef STEP
#undef LD4

    if (tid == 0) outp[b] = out_r;
}

// ---------------------------------------------------------------------------
// Fallback (known-passing round-2 kernel): fused recurrence, 2 MB ws.
__global__ __launch_bounds__(256) void sig_transpose(const float* __restrict__ ntp,
                                                     u32* __restrict__ out) {
    __shared__ float lds[64 * 65];
    const int nm0 = blockIdx.x * 64;
    const int tid = threadIdx.x;
    #pragma unroll
    for (int it = 0; it < 16; ++it) {
        int idx = it * 256 + tid;
        int r = idx >> 6, c = idx & 63;
        lds[r * 65 + c] = sigf(ntp[(nm0 + r) * 64 + c]);
    }
    __syncthreads();
    #pragma unroll
    for (int it = 0; it < 8; ++it) {
        int o = it * 256 + tid;
        int tpi = o >> 6, r = o & 63;
        f16x2 h;
        h[0] = (f16)lds[r * 65 + 2 * tpi];
        h[1] = (f16)lds[r * 65 + 2 * tpi + 1];
        out[tpi * NM + nm0 + r] = __builtin_bit_cast(u32, h);
    }
}

__global__ __launch_bounds__(1024) void grammar_fused(
    const float* __restrict__ x_all,
    const float* __restrict__ tp,
    const u32*  __restrict__ ntpT2,
    float* __restrict__ outp) {
    __shared__ float x_lds[LL * TT];
    __shared__ float prevbuf[2][NN];
    __shared__ u32 x2_lds[2][32];

    const int b = blockIdx.x;
    const int tid = threadIdx.x;
    const int lane16 = tid & 15;
    const int g = tid >> 4;
    const int mbase = lane16 * 8;

    const float* xb = x_all + b * (LL * TT);
    #pragma unroll
    for (int it = 0; it < 8; ++it) {
        int idx = it * 1024 + tid;
        x_lds[idx] = xb[idx];
    }
    __syncthreads();

    if (tid < NN) {
        float acc = 0.f;
        #pragma unroll 8
        for (int t = 0; t < TT; ++t)
            acc += sigf(tp[tid * TT + t]) * x_lds[t];
        prevbuf[0][tid] = acc;
    }
    __syncthreads();
    float out_r = 0.f;
    if (tid == 0) out_r = prevbuf[0][0];

    int p = 0;
    for (int i0 = 1; i0 < LL; i0 += 2) {
        const int ns = (LL - i0) >= 2 ? 2 : 1;
        if (tid < 64) {
            int s = tid >> 5, tpi = tid & 31;
            f16x2 h;
            if (s < ns) {
                h[0] = (f16)x_lds[(i0 + s) * TT + 2 * tpi];
                h[1] = (f16)x_lds[(i0 + s) * TT + 2 * tpi + 1];
            } else {
                h[0] = (f16)0.f; h[1] = (f16)0.f;
            }
            x2_lds[s][tpi] = __builtin_bit_cast(u32, h);
        }
        __syncthreads();

        float acc[2][2][8];
        #pragma unroll
        for (int k = 0; k < 2; ++k)
            #pragma unroll
            for (int s = 0; s < 2; ++s)
                #pragma unroll
                for (int j = 0; j < 8; ++j) acc[k][s][j] = 0.f;

        #pragma unroll 2
        for (int tpi = 0; tpi < 32; ++tpi) {
            f16x2 xv0 = __builtin_bit_cast(f16x2, x2_lds[0][tpi]);
            f16x2 xv1 = __builtin_bit_cast(f16x2, x2_lds[1][tpi]);
            const u32* base = ntpT2 + tpi * NM + 8 * tid;
            #pragma unroll
            for (int k = 0; k < 2; ++k) {
                uint4 w0 = *reinterpret_cast<const uint4*>(base + 8192 * k);
                uint4 w1 = *reinterpret_cast<const uint4*>(base + 8192 * k + 4);
                u32 wv[8] = {w0.x, w0.y, w0.z, w0.w, w1.x, w1.y, w1.z, w1.w};
                #pragma unroll
                for (int j = 0; j < 8; ++j) {
                    f16x2 w = __builtin_bit_cast(f16x2, wv[j]);
                    acc[k][0][j] = fdot2f(w, xv0, acc[k][0][j]);
                    acc[k][1][j] = fdot2f(w, xv1, acc[k][1][j]);
                }
            }
        }

        for (int s = 0; s < ns; ++s) {
            float4 pv0 = *reinterpret_cast<const float4*>(&prevbuf[p][mbase]);
            float4 pv1 = *reinterpret_cast<const float4*>(&prevbuf[p][mbase + 4]);
            float pvv[8] = {pv0.x, pv0.y, pv0.z, pv0.w, pv1.x, pv1.y, pv1.z, pv1.w};
            #pragma unroll
            for (int k = 0; k < 2; ++k) {
                float part = 0.f;
                #pragma unroll
                for (int j = 0; j < 8; ++j) {
                    float npcv = clip01(acc[k][s][j]);
                    part += npcv * pvv[j];
                }
                part += __shfl_xor(part, 1);
                part += __shfl_xor(part, 2);
                part += __shfl_xor(part, 4);
                part += __shfl_xor(part, 8);
                if (lane16 == 0) {
                    float c = clip01(part);
                    prevbuf[p ^ 1][g + 64 * k] = c;
                    if (tid == 0 && k == 0) {
                        float mask = x_lds[(i0 + s) * TT + 63];
                        out_r = out_r * mask + c * (1.f - mask);
                    }
                }
            }
            p ^= 1;
            __syncthreads();
        }
    }

    if (tid == 0) outp[b] = out_r;
}

// ---------------------------------------------------------------------------
extern "C" void kernel_launch(void* const* d_in, const int* in_sizes, int n_in,
                              void* d_out, int out_size, void* d_ws, size_t ws_size,
                              hipStream_t stream) {
    const float* input_tensor = (const float*)d_in[0];   // [64][128][64]
    const float* term_prod    = (const float*)d_in[1];   // [128][64]
    const float* nonterm_prod = (const float*)d_in[2];   // [128][128][64]
    float* outp = (float*)d_out;                         // [64]

    const size_t MB = 1024 * 1024;
    const size_t NPC_BYTES = 128 * MB;   // 64 b x 1024 tiles x 2048 B
    const size_t WPK_BYTES = 2 * MB;     // bf16 A-frags
    const size_t XPK_BYTES = 1 * MB;     // bf16 B-frags

    if (ws_size >= NPC_BYTES + WPK_BYTES + XPK_BYTES + MB) {
        u8* npcbuf  = (u8*)d_ws;
        ushort* wpk = (ushort*)((char*)d_ws + NPC_BYTES);
        ushort* xpk = (ushort*)((char*)d_ws + NPC_BYTES + WPK_BYTES);
        pack_w<<<512, 256, 0, stream>>>(nonterm_prod, wpk);
        pack_x<<<256, 256, 0, stream>>>(input_tensor, xpk);
        gemm_mfma<<<1024, 256, 0, stream>>>(wpk, xpk, npcbuf);
        recur3<<<BB, 1024, 0, stream>>>(input_tensor, term_prod, npcbuf, outp);
    } else {
        u32* ntpT2 = (u32*)d_ws;
        sig_transpose<<<256, 256, 0, stream>>>(nonterm_prod, ntpT2);
        grammar_fused<<<BB, 1024, 0, stream>>>(input_tensor, term_prod, ntpT2, outp);
    }
}

// Round 7
// 146.968 us; speedup vs baseline: 1.3890x; 1.3890x over previous
//
#include <hip/hip_runtime.h>
#include <hip/hip_bf16.h>

typedef unsigned int u32;
typedef unsigned char u8;
typedef _Float16 f16;
typedef f16 f16x2 __attribute__((ext_vector_type(2)));
typedef short s16x8 __attribute__((ext_vector_type(8)));
typedef float f32x4 __attribute__((ext_vector_type(4)));

#define BB 64
#define LL 128
#define TT 64
#define NN 128
#define NM (NN*NN)   // 16384

__device__ __forceinline__ float sigf(float v) {
    return 1.0f / (1.0f + __expf(-v));
}

__device__ __forceinline__ float clip01(float v) {
    return fminf(fmaxf(v, 0.f), 1.f);
}

__device__ __forceinline__ u32 f2bf(float f) {   // f32 -> bf16 bits (RNE)
    u32 u = __builtin_bit_cast(u32, f);
    return (u + 0x7fffu + ((u >> 16) & 1u)) >> 16;
}

__device__ __forceinline__ float fdot2f(f16x2 wa, f16x2 xa, float ca) {
#if defined(__HIP_DEVICE_COMPILE__) && __has_builtin(__builtin_amdgcn_fdot2)
    return __builtin_amdgcn_fdot2(wa, xa, ca, false);
#else
    return ca + (float)wa[0] * (float)xa[0] + (float)wa[1] * (float)xa[1];
#endif
}

__device__ __forceinline__ u32 ud4(u32 a, u32 b, u32 c) {   // 4x u8 dot + acc
#if defined(__HIP_DEVICE_COMPILE__) && __has_builtin(__builtin_amdgcn_udot4)
    return __builtin_amdgcn_udot4(a, b, c, false);
#else
    return c + (a & 255u) * (b & 255u) + ((a >> 8) & 255u) * ((b >> 8) & 255u)
             + ((a >> 16) & 255u) * ((b >> 16) & 255u) + (a >> 24) * (b >> 24);
#endif
}

// ---------------------------------------------------------------------------
// pack_w: sigmoid(ntp) -> bf16 A-fragment order for mfma_f32_16x16x32_bf16.
__global__ __launch_bounds__(256) void pack_w(const float* __restrict__ ntp,
                                              ushort* __restrict__ wpk) {
    const int g = blockIdx.x * 256 + threadIdx.x;   // 0..131071
    const int l = g & 63, h = (g >> 6) & 1, i = g >> 7;
    const int row = i * 16 + (l & 15);
    const int t0 = h * 32 + ((l >> 4) << 3);
    const float* src = ntp + row * 64 + t0;
    float4 f0 = *reinterpret_cast<const float4*>(src);
    float4 f1 = *reinterpret_cast<const float4*>(src + 4);
    float v[8] = {f0.x, f0.y, f0.z, f0.w, f1.x, f1.y, f1.z, f1.w};
    u32 o[4];
    #pragma unroll
    for (int q = 0; q < 4; ++q)
        o[q] = f2bf(sigf(v[2 * q])) | (f2bf(sigf(v[2 * q + 1])) << 16);
    uint4 ov; ov.x = o[0]; ov.y = o[1]; ov.z = o[2]; ov.w = o[3];
    *reinterpret_cast<uint4*>(wpk + (size_t)g * 8) = ov;
}

// ---------------------------------------------------------------------------
// pack_x: x -> bf16 B-fragment order.
__global__ __launch_bounds__(256) void pack_x(const float* __restrict__ x_all,
                                              ushort* __restrict__ xpk) {
    const int g = blockIdx.x * 256 + threadIdx.x;   // 0..65535
    const int l = g & 63, h = (g >> 6) & 1, j = (g >> 7) & 7, b = g >> 10;
    const int s = j * 16 + (l & 15);
    const int t0 = h * 32 + ((l >> 4) << 3);
    const float* src = x_all + ((size_t)b * LL + s) * TT + t0;
    float4 f0 = *reinterpret_cast<const float4*>(src);
    float4 f1 = *reinterpret_cast<const float4*>(src + 4);
    float v[8] = {f0.x, f0.y, f0.z, f0.w, f1.x, f1.y, f1.z, f1.w};
    u32 o[4];
    #pragma unroll
    for (int q = 0; q < 4; ++q)
        o[q] = f2bf(v[2 * q]) | (f2bf(v[2 * q + 1]) << 16);
    uint4 ov; ov.x = o[0]; ov.y = o[1]; ov.z = o[2]; ov.w = o[3];
    *reinterpret_cast<uint4*>(xpk + (size_t)g * 8) = ov;
}

// ---------------------------------------------------------------------------
// gemm_mfma with layout N': npc address =
//   b*2MB + j*256KB + l*4KB + k*256 + c*16 + e
// where j = s>>4, c = s&15, l = n&63, k = (m>>4) + 8*(n>>6), e = m&15.
// Per (tile,j) wave store: 64 lanes cover exactly one 256-B block. Coalesced.
__global__ __launch_bounds__(256) void gemm_mfma(const ushort* __restrict__ wpk,
                                                 const ushort* __restrict__ xpk,
                                                 u8* __restrict__ npc) {
    const int b = blockIdx.x >> 4;
    const int nb = blockIdx.x & 15;
    const int wv = threadIdx.x >> 6, l = threadIdx.x & 63;

    uint4 xf[8][2];
    #pragma unroll
    for (int j = 0; j < 8; ++j)
        #pragma unroll
        for (int h = 0; h < 2; ++h)
            xf[j][h] = *reinterpret_cast<const uint4*>(
                xpk + (size_t)(((b * 8 + j) * 2 + h) * 64 + l) * 8);

    const int c = l & 15, r0 = (l >> 4) * 4;

    for (int it = 0; it < 16; ++it) {
        const int i = nb * 64 + wv * 16 + it;        // nm-tile index 0..1023
        uint4 a0 = *reinterpret_cast<const uint4*>(wpk + (size_t)((i * 2 + 0) * 64 + l) * 8);
        uint4 a1 = *reinterpret_cast<const uint4*>(wpk + (size_t)((i * 2 + 1) * 64 + l) * 8);
        f32x4 acc[8];
        const f32x4 z = {0.f, 0.f, 0.f, 0.f};
        #pragma unroll
        for (int j = 0; j < 8; ++j)
            acc[j] = __builtin_amdgcn_mfma_f32_16x16x32_bf16(
                __builtin_bit_cast(s16x8, a0), __builtin_bit_cast(s16x8, xf[j][0]), z, 0, 0, 0);
        #pragma unroll
        for (int j = 0; j < 8; ++j)
            acc[j] = __builtin_amdgcn_mfma_f32_16x16x32_bf16(
                __builtin_bit_cast(s16x8, a1), __builtin_bit_cast(s16x8, xf[j][1]), acc[j], 0, 0, 0);

        const int k   = (i & 7) + 8 * (i >> 9);      // mgroup + 8*(n>>6)
        const int lst = (i >> 3) & 63;               // n & 63
        u8* p0 = npc + ((size_t)b << 21) + (((size_t)lst << 4) + k) * 256
                     + (c << 4) + r0;
        #pragma unroll
        for (int j = 0; j < 8; ++j) {
            u32 w = 0;
            #pragma unroll
            for (int r = 0; r < 4; ++r) {
                float q = clip01(acc[j][r]) * 255.f + 0.5f;
                w |= ((u32)q) << (8 * r);
            }
            *reinterpret_cast<u32*>(p0 + ((size_t)j << 18)) = w;   // j*256KB
        }
    }
}

// ---------------------------------------------------------------------------
// recur4: one wave per batch. Lane l owns rows n=l and n=64+l; each lane
// computes its full 128-length dot via v_dot4_u32_u8 -> no reduction, no
// block barrier. prev u8 broadcast via LDS; npc prefetched depth-3 in regs.
__global__ __launch_bounds__(64) void recur4(const float* __restrict__ x_all,
                                             const float* __restrict__ tp,
                                             const u8* __restrict__ npc,
                                             float* __restrict__ outp) {
    __shared__ __align__(16) u8 prev_lds[2][128];
    __shared__ float masks_lds[128];
    __shared__ float tpc_lds[128];
    __shared__ float x0_lds[64];

    const int b = blockIdx.x, l = threadIdx.x;
    const u8* npcb = npc + ((size_t)b << 21) + ((size_t)l << 12);

    // one-time staging
    x0_lds[l] = x_all[(size_t)b * 8192 + l];
    masks_lds[l]      = x_all[(size_t)b * 8192 + l * 64 + 63];
    masks_lds[64 + l] = x_all[(size_t)b * 8192 + (64 + l) * 64 + 63];
    asm volatile("s_waitcnt lgkmcnt(0)" ::: "memory");
    __builtin_amdgcn_sched_barrier(0);

#define LOADSET(R, T) do { \
        int _t = (T) <= 127 ? (T) : 127; \
        const u8* _p = npcb + ((size_t)(_t >> 4) << 18) + ((_t & 15) << 4); \
        _Pragma("unroll") \
        for (int _k = 0; _k < 16; ++_k) \
            R[_k] = *reinterpret_cast<const uint4*>(_p + _k * 256); \
    } while (0)

    uint4 nA[16], nB[16], nC[16];
    LOADSET(nA, 1);          // issue early; tpc compute hides latency

    // tpc (exact f32): lane l -> n=l and n=64+l
    float a0 = 0.f, a1 = 0.f;
    #pragma unroll
    for (int t4 = 0; t4 < 16; ++t4) {
        float4 xv = *reinterpret_cast<const float4*>(x0_lds + t4 * 4);
        float4 w0 = *reinterpret_cast<const float4*>(tp + l * 64 + t4 * 4);
        float4 w1 = *reinterpret_cast<const float4*>(tp + (64 + l) * 64 + t4 * 4);
        a0 += sigf(w0.x) * xv.x; a0 += sigf(w0.y) * xv.y;
        a0 += sigf(w0.z) * xv.z; a0 += sigf(w0.w) * xv.w;
        a1 += sigf(w1.x) * xv.x; a1 += sigf(w1.y) * xv.y;
        a1 += sigf(w1.z) * xv.z; a1 += sigf(w1.w) * xv.w;
    }
    tpc_lds[l] = a0; tpc_lds[64 + l] = a1;
    float out_r = a0;                       // lane 0 holds tpc[0]
    asm volatile("s_waitcnt lgkmcnt(0)" ::: "memory");
    __builtin_amdgcn_sched_barrier(0);

    // step 1: cur1 = clip01(npc1 . tpc), tpc in f32 (unclipped range)
    {
        float s0f = 0.f, s1f = 0.f;
        #pragma unroll
        for (int k = 0; k < 8; ++k) {
            u32 ax[4] = {nA[k].x, nA[k].y, nA[k].z, nA[k].w};
            u32 bx[4] = {nA[k + 8].x, nA[k + 8].y, nA[k + 8].z, nA[k + 8].w};
            #pragma unroll
            for (int w = 0; w < 4; ++w) {
                float4 tv = *reinterpret_cast<const float4*>(tpc_lds + k * 16 + w * 4);
                u32 aw = ax[w], bw = bx[w];
                s0f += (float)(aw & 255u) * tv.x + (float)((aw >> 8) & 255u) * tv.y
                     + (float)((aw >> 16) & 255u) * tv.z + (float)(aw >> 24) * tv.w;
                s1f += (float)(bw & 255u) * tv.x + (float)((bw >> 8) & 255u) * tv.y
                     + (float)((bw >> 16) & 255u) * tv.z + (float)(bw >> 24) * tv.w;
            }
        }
        float c0 = clip01(s0f * (1.f / 255.f));
        float c1 = clip01(s1f * (1.f / 255.f));
        float mk = masks_lds[1];
        if (l == 0) out_r = out_r * mk + c0 * (1.f - mk);
        prev_lds[0][l]      = (u8)(c0 * 255.f + 0.5f);
        prev_lds[0][64 + l] = (u8)(c1 * 255.f + 0.5f);
        asm volatile("s_waitcnt lgkmcnt(0)" ::: "memory");
        __builtin_amdgcn_sched_barrier(0);
    }

    int p = 0;
    LOADSET(nA, 2); LOADSET(nB, 3); LOADSET(nC, 4);

#define STEP(R, S) do { \
        uint4 pv[8]; \
        _Pragma("unroll") \
        for (int _q = 0; _q < 8; ++_q) \
            pv[_q] = *reinterpret_cast<const uint4*>(&prev_lds[p][_q * 16]); \
        float mk = masks_lds[(S)]; \
        u32 s0 = 0, t0 = 0, s1 = 0, t1 = 0; \
        _Pragma("unroll") \
        for (int _k = 0; _k < 4; ++_k) { \
            s0 = ud4(R[_k].x, pv[_k].x, s0); s0 = ud4(R[_k].y, pv[_k].y, s0); \
            s0 = ud4(R[_k].z, pv[_k].z, s0); s0 = ud4(R[_k].w, pv[_k].w, s0); \
        } \
        _Pragma("unroll") \
        for (int _k = 4; _k < 8; ++_k) { \
            t0 = ud4(R[_k].x, pv[_k].x, t0); t0 = ud4(R[_k].y, pv[_k].y, t0); \
            t0 = ud4(R[_k].z, pv[_k].z, t0); t0 = ud4(R[_k].w, pv[_k].w, t0); \
        } \
        _Pragma("unroll") \
        for (int _k = 8; _k < 12; ++_k) { \
            s1 = ud4(R[_k].x, pv[_k - 8].x, s1); s1 = ud4(R[_k].y, pv[_k - 8].y, s1); \
            s1 = ud4(R[_k].z, pv[_k - 8].z, s1); s1 = ud4(R[_k].w, pv[_k - 8].w, s1); \
        } \
        _Pragma("unroll") \
        for (int _k = 12; _k < 16; ++_k) { \
            t1 = ud4(R[_k].x, pv[_k - 8].x, t1); t1 = ud4(R[_k].y, pv[_k - 8].y, t1); \
            t1 = ud4(R[_k].z, pv[_k - 8].z, t1); t1 = ud4(R[_k].w, pv[_k - 8].w, t1); \
        } \
        float c0 = fminf((float)(s0 + t0) * (1.f / 65025.f), 1.f); \
        float c1 = fminf((float)(s1 + t1) * (1.f / 65025.f), 1.f); \
        u32 q0 = (u32)(c0 * 255.f + 0.5f), q1 = (u32)(c1 * 255.f + 0.5f); \
        if (l == 0) out_r = out_r * mk + c0 * (1.f - mk); \
        prev_lds[p ^ 1][l]      = (u8)q0; \
        prev_lds[p ^ 1][64 + l] = (u8)q1; \
        asm volatile("s_waitcnt lgkmcnt(0)" ::: "memory"); \
        __builtin_amdgcn_sched_barrier(0); \
        p ^= 1; \
    } while (0)

    for (int g = 0; g < 42; ++g) {
        const int s = 2 + 3 * g;
        STEP(nA, s);     LOADSET(nA, s + 3);
        STEP(nB, s + 1); LOADSET(nB, s + 4);
        STEP(nC, s + 2); LOADSET(nC, s + 5);
    }
#undef STEP
#undef LOADSET

    if (l == 0) outp[b] = out_r;
}

// ---------------------------------------------------------------------------
// Fallback (known-passing round-2 kernel): fused recurrence, 2 MB ws.
__global__ __launch_bounds__(256) void sig_transpose(const float* __restrict__ ntp,
                                                     u32* __restrict__ out) {
    __shared__ float lds[64 * 65];
    const int nm0 = blockIdx.x * 64;
    const int tid = threadIdx.x;
    #pragma unroll
    for (int it = 0; it < 16; ++it) {
        int idx = it * 256 + tid;
        int r = idx >> 6, c = idx & 63;
        lds[r * 65 + c] = sigf(ntp[(nm0 + r) * 64 + c]);
    }
    __syncthreads();
    #pragma unroll
    for (int it = 0; it < 8; ++it) {
        int o = it * 256 + tid;
        int tpi = o >> 6, r = o & 63;
        f16x2 h;
        h[0] = (f16)lds[r * 65 + 2 * tpi];
        h[1] = (f16)lds[r * 65 + 2 * tpi + 1];
        out[tpi * NM + nm0 + r] = __builtin_bit_cast(u32, h);
    }
}

__global__ __launch_bounds__(1024) void grammar_fused(
    const float* __restrict__ x_all,
    const float* __restrict__ tp,
    const u32*  __restrict__ ntpT2,
    float* __restrict__ outp) {
    __shared__ float x_lds[LL * TT];
    __shared__ float prevbuf[2][NN];
    __shared__ u32 x2_lds[2][32];

    const int b = blockIdx.x;
    const int tid = threadIdx.x;
    const int lane16 = tid & 15;
    const int g = tid >> 4;
    const int mbase = lane16 * 8;

    const float* xb = x_all + b * (LL * TT);
    #pragma unroll
    for (int it = 0; it < 8; ++it) {
        int idx = it * 1024 + tid;
        x_lds[idx] = xb[idx];
    }
    __syncthreads();

    if (tid < NN) {
        float acc = 0.f;
        #pragma unroll 8
        for (int t = 0; t < TT; ++t)
            acc += sigf(tp[tid * TT + t]) * x_lds[t];
        prevbuf[0][tid] = acc;
    }
    __syncthreads();
    float out_r = 0.f;
    if (tid == 0) out_r = prevbuf[0][0];

    int p = 0;
    for (int i0 = 1; i0 < LL; i0 += 2) {
        const int ns = (LL - i0) >= 2 ? 2 : 1;
        if (tid < 64) {
            int s = tid >> 5, tpi = tid & 31;
            f16x2 h;
            if (s < ns) {
                h[0] = (f16)x_lds[(i0 + s) * TT + 2 * tpi];
                h[1] = (f16)x_lds[(i0 + s) * TT + 2 * tpi + 1];
            } else {
                h[0] = (f16)0.f; h[1] = (f16)0.f;
            }
            x2_lds[s][tpi] = __builtin_bit_cast(u32, h);
        }
        __syncthreads();

        float acc[2][2][8];
        #pragma unroll
        for (int k = 0; k < 2; ++k)
            #pragma unroll
            for (int s = 0; s < 2; ++s)
                #pragma unroll
                for (int j = 0; j < 8; ++j) acc[k][s][j] = 0.f;

        #pragma unroll 2
        for (int tpi = 0; tpi < 32; ++tpi) {
            f16x2 xv0 = __builtin_bit_cast(f16x2, x2_lds[0][tpi]);
            f16x2 xv1 = __builtin_bit_cast(f16x2, x2_lds[1][tpi]);
            const u32* base = ntpT2 + tpi * NM + 8 * tid;
            #pragma unroll
            for (int k = 0; k < 2; ++k) {
                uint4 w0 = *reinterpret_cast<const uint4*>(base + 8192 * k);
                uint4 w1 = *reinterpret_cast<const uint4*>(base + 8192 * k + 4);
                u32 wv[8] = {w0.x, w0.y, w0.z, w0.w, w1.x, w1.y, w1.z, w1.w};
                #pragma unroll
                for (int j = 0; j < 8; ++j) {
                    f16x2 w = __builtin_bit_cast(f16x2, wv[j]);
                    acc[k][0][j] = fdot2f(w, xv0, acc[k][0][j]);
                    acc[k][1][j] = fdot2f(w, xv1, acc[k][1][j]);
                }
            }
        }

        for (int s = 0; s < ns; ++s) {
            float4 pv0 = *reinterpret_cast<const float4*>(&prevbuf[p][mbase]);
            float4 pv1 = *reinterpret_cast<const float4*>(&prevbuf[p][mbase + 4]);
            float pvv[8] = {pv0.x, pv0.y, pv0.z, pv0.w, pv1.x, pv1.y, pv1.z, pv1.w};
            #pragma unroll
            for (int k = 0; k < 2; ++k) {
                float part = 0.f;
                #pragma unroll
                for (int j = 0; j < 8; ++j) {
                    float npcv = clip01(acc[k][s][j]);
                    part += npcv * pvv[j];
                }
                part += __shfl_xor(part, 1);
                part += __shfl_xor(part, 2);
                part += __shfl_xor(part, 4);
                part += __shfl_xor(part, 8);
                if (lane16 == 0) {
                    float c = clip01(part);
                    prevbuf[p ^ 1][g + 64 * k] = c;
                    if (tid == 0 && k == 0) {
                        float mask = x_lds[(i0 + s) * TT + 63];
                        out_r = out_r * mask + c * (1.f - mask);
                    }
                }
            }
            p ^= 1;
            __syncthreads();
        }
    }

    if (tid == 0) outp[b] = out_r;
}

// ---------------------------------------------------------------------------
extern "C" void kernel_launch(void* const* d_in, const int* in_sizes, int n_in,
                              void* d_out, int out_size, void* d_ws, size_t ws_size,
                              hipStream_t stream) {
    const float* input_tensor = (const float*)d_in[0];   // [64][128][64]
    const float* term_prod    = (const float*)d_in[1];   // [128][64]
    const float* nonterm_prod = (const float*)d_in[2];   // [128][128][64]
    float* outp = (float*)d_out;                         // [64]

    const size_t MB = 1024 * 1024;
    const size_t NPC_BYTES = 128 * MB;   // layout N': b*2MB + j*256KB + l*4KB + k*256
    const size_t WPK_BYTES = 2 * MB;     // bf16 A-frags
    const size_t XPK_BYTES = 1 * MB;     // bf16 B-frags

    if (ws_size >= NPC_BYTES + WPK_BYTES + XPK_BYTES + MB) {
        u8* npcbuf  = (u8*)d_ws;
        ushort* wpk = (ushort*)((char*)d_ws + NPC_BYTES);
        ushort* xpk = (ushort*)((char*)d_ws + NPC_BYTES + WPK_BYTES);
        pack_w<<<512, 256, 0, stream>>>(nonterm_prod, wpk);
        pack_x<<<256, 256, 0, stream>>>(input_tensor, xpk);
        gemm_mfma<<<1024, 256, 0, stream>>>(wpk, xpk, npcbuf);
        recur4<<<BB, 64, 0, stream>>>(input_tensor, term_prod, npcbuf, outp);
    } else {
        u32* ntpT2 = (u32*)d_ws;
        sig_transpose<<<256, 256, 0, stream>>>(nonterm_prod, ntpT2);
        grammar_fused<<<BB, 1024, 0, stream>>>(input_tensor, term_prod, ntpT2, outp);
    }
}

// Round 8
// 93.590 us; speedup vs baseline: 2.1811x; 1.5703x over previous
//
#include <hip/hip_runtime.h>
#include <hip/hip_bf16.h>

typedef unsigned int u32;
typedef unsigned char u8;
typedef _Float16 f16;
typedef f16 f16x2 __attribute__((ext_vector_type(2)));
typedef short s16x8 __attribute__((ext_vector_type(8)));
typedef float f32x4 __attribute__((ext_vector_type(4)));

#define BB 64
#define LL 128
#define TT 64
#define NN 128
#define NM (NN*NN)   // 16384

__device__ __forceinline__ float sigf(float v) {
    return 1.0f / (1.0f + __expf(-v));
}

__device__ __forceinline__ float clip01(float v) {
    return fminf(fmaxf(v, 0.f), 1.f);
}

__device__ __forceinline__ u32 f2bf(float f) {   // f32 -> bf16 bits (RNE)
    u32 u = __builtin_bit_cast(u32, f);
    return (u + 0x7fffu + ((u >> 16) & 1u)) >> 16;
}

__device__ __forceinline__ float fdot2f(f16x2 wa, f16x2 xa, float ca) {
#if defined(__HIP_DEVICE_COMPILE__) && __has_builtin(__builtin_amdgcn_fdot2)
    return __builtin_amdgcn_fdot2(wa, xa, ca, false);
#else
    return ca + (float)wa[0] * (float)xa[0] + (float)wa[1] * (float)xa[1];
#endif
}

__device__ __forceinline__ u32 ud4(u32 a, u32 b, u32 c) {   // 4x u8 dot + acc
#if defined(__HIP_DEVICE_COMPILE__) && __has_builtin(__builtin_amdgcn_udot4)
    return __builtin_amdgcn_udot4(a, b, c, false);
#else
    return c + (a & 255u) * (b & 255u) + ((a >> 8) & 255u) * ((b >> 8) & 255u)
             + ((a >> 16) & 255u) * ((b >> 16) & 255u) + (a >> 24) * (b >> 24);
#endif
}

// ---------------------------------------------------------------------------
// pack_w: sigmoid(ntp) -> bf16 A-fragment order for mfma_f32_16x16x32_bf16.
// Tile i = n*8+mg covers nm = i*16 + r (n = i>>3, m = mg*16 + r).
__global__ __launch_bounds__(256) void pack_w(const float* __restrict__ ntp,
                                              ushort* __restrict__ wpk) {
    const int g = blockIdx.x * 256 + threadIdx.x;   // 0..131071
    const int l = g & 63, h = (g >> 6) & 1, i = g >> 7;
    const int row = i * 16 + (l & 15);
    const int t0 = h * 32 + ((l >> 4) << 3);
    const float* src = ntp + row * 64 + t0;
    float4 f0 = *reinterpret_cast<const float4*>(src);
    float4 f1 = *reinterpret_cast<const float4*>(src + 4);
    float v[8] = {f0.x, f0.y, f0.z, f0.w, f1.x, f1.y, f1.z, f1.w};
    u32 o[4];
    #pragma unroll
    for (int q = 0; q < 4; ++q)
        o[q] = f2bf(sigf(v[2 * q])) | (f2bf(sigf(v[2 * q + 1])) << 16);
    uint4 ov; ov.x = o[0]; ov.y = o[1]; ov.z = o[2]; ov.w = o[3];
    *reinterpret_cast<uint4*>(wpk + (size_t)g * 8) = ov;
}

// ---------------------------------------------------------------------------
// pack_x: x -> bf16 B-fragment order.
__global__ __launch_bounds__(256) void pack_x(const float* __restrict__ x_all,
                                              ushort* __restrict__ xpk) {
    const int g = blockIdx.x * 256 + threadIdx.x;   // 0..65535
    const int l = g & 63, h = (g >> 6) & 1, j = (g >> 7) & 7, b = g >> 10;
    const int s = j * 16 + (l & 15);
    const int t0 = h * 32 + ((l >> 4) << 3);
    const float* src = x_all + ((size_t)b * LL + s) * TT + t0;
    float4 f0 = *reinterpret_cast<const float4*>(src);
    float4 f1 = *reinterpret_cast<const float4*>(src + 4);
    float v[8] = {f0.x, f0.y, f0.z, f0.w, f1.x, f1.y, f1.z, f1.w};
    u32 o[4];
    #pragma unroll
    for (int q = 0; q < 4; ++q)
        o[q] = f2bf(v[2 * q]) | (f2bf(v[2 * q + 1]) << 16);
    uint4 ov; ov.x = o[0]; ov.y = o[1]; ov.z = o[2]; ov.w = o[3];
    *reinterpret_cast<uint4*>(xpk + (size_t)g * 8) = ov;
}

// ---------------------------------------------------------------------------
// gemm_mfma, layout R:
//   npc byte(b,s,n,m) = b<<21 | (s>>4)<<18 | (s&15)<<14
//                       | ((m>>4) + 8*(n>>6))<<10 | (n&63)<<4 | (m&15)
// Recur lanes read 1KB-contiguous runs; the store-side scatter is resolved by a
// wave-private LDS transpose (16 KB/wave, no barriers):
//   LDS byte = wv*16384 + j*2048 + c*128 + ((n_l + c)&7)*16 + e   (skewed)
// Write: lane (c=l&15, r0=(l>>4)*4) -> 2-way bank (free). Read: lane-linear
// b128 per 8-lane group (conflict-free). Flush store: 8-lane 128B runs.
// Grid 1024 wgs = (b 64) x (nb 16); wave wv owns mgroups {2wv,2wv+1} x 8 n.
__global__ __launch_bounds__(256) void gemm_mfma(const ushort* __restrict__ wpk,
                                                 const ushort* __restrict__ xpk,
                                                 u8* __restrict__ npc) {
    __shared__ __align__(16) u8 stg[4][16384];
    const int b = blockIdx.x >> 4;
    const int nb = blockIdx.x & 15;
    const int wv = threadIdx.x >> 6, l = threadIdx.x & 63;

    uint4 xf[8][2];
    #pragma unroll
    for (int j = 0; j < 8; ++j)
        #pragma unroll
        for (int h = 0; h < 2; ++h)
            xf[j][h] = *reinterpret_cast<const uint4*>(
                xpk + (size_t)(((b * 8 + j) * 2 + h) * 64 + l) * 8);

    const int c = l & 15, r0 = (l >> 4) * 4;
    u8* stw = stg[wv];
    const int khi  = (nb >> 3) * 8;
    const int nlow = (nb & 7) * 8;

    for (int mg2 = 0; mg2 < 2; ++mg2) {
        const int mg = wv * 2 + mg2;
        #pragma unroll
        for (int n_l = 0; n_l < 8; ++n_l) {
            const int i = (nb * 8 + n_l) * 8 + mg;   // tile index
            uint4 a0 = *reinterpret_cast<const uint4*>(wpk + (size_t)((i * 2 + 0) * 64 + l) * 8);
            uint4 a1 = *reinterpret_cast<const uint4*>(wpk + (size_t)((i * 2 + 1) * 64 + l) * 8);
            const f32x4 z = {0.f, 0.f, 0.f, 0.f};
            f32x4 acc[8];
            #pragma unroll
            for (int j = 0; j < 8; ++j)
                acc[j] = __builtin_amdgcn_mfma_f32_16x16x32_bf16(
                    __builtin_bit_cast(s16x8, a0), __builtin_bit_cast(s16x8, xf[j][0]), z, 0, 0, 0);
            #pragma unroll
            for (int j = 0; j < 8; ++j)
                acc[j] = __builtin_amdgcn_mfma_f32_16x16x32_bf16(
                    __builtin_bit_cast(s16x8, a1), __builtin_bit_cast(s16x8, xf[j][1]), acc[j], 0, 0, 0);

            const int sk = (((n_l + c) & 7) << 4) + r0;
            #pragma unroll
            for (int j = 0; j < 8; ++j) {
                u32 w = 0;
                #pragma unroll
                for (int r = 0; r < 4; ++r) {
                    float q = clip01(acc[j][r]) * 255.f + 0.5f;
                    w |= ((u32)q) << (8 * r);
                }
                *reinterpret_cast<u32*>(stw + j * 2048 + c * 128 + sk) = w;
            }
        }
        asm volatile("s_waitcnt lgkmcnt(0)" ::: "memory");
        __builtin_amdgcn_sched_barrier(0);

        // flush: 16 coalesced dwordx4 stores (8-lane 128B runs)
        const int nr = l & 7;
        #pragma unroll
        for (int j = 0; j < 8; ++j) {
            #pragma unroll
            for (int half = 0; half < 2; ++half) {
                const int cc = half * 8 + (l >> 3);
                uint4 v = *reinterpret_cast<const uint4*>(
                    stw + j * 2048 + cc * 128 + (((nr + cc) & 7) << 4));
                *reinterpret_cast<uint4*>(npc + ((size_t)b << 21) + ((size_t)j << 18)
                    + ((size_t)cc << 14) + ((size_t)(mg + khi) << 10)
                    + ((nlow + nr) << 4)) = v;
            }
        }
        asm volatile("s_waitcnt lgkmcnt(0)" ::: "memory");
        __builtin_amdgcn_sched_barrier(0);
    }
}

// ---------------------------------------------------------------------------
// recur4: one wave per batch; lane l owns rows n=l, 64+l; 64 udot4/step;
// layout-R loads: 16 x 1KB-contiguous coalesced dwordx4; depth-2 prefetch.
__global__ __launch_bounds__(64) void recur4(const float* __restrict__ x_all,
                                             const float* __restrict__ tp,
                                             const u8* __restrict__ npc,
                                             float* __restrict__ outp) {
    __shared__ __align__(16) u8 prev_lds[2][128];
    __shared__ float masks_lds[128];
    __shared__ float tpc_lds[128];
    __shared__ float x0_lds[64];

    const int b = blockIdx.x, l = threadIdx.x;
    const u8* npcl = npc + ((size_t)b << 21) + ((size_t)l << 4);

    // one-time staging
    x0_lds[l] = x_all[(size_t)b * 8192 + l];
    masks_lds[l]      = x_all[(size_t)b * 8192 + l * 64 + 63];
    masks_lds[64 + l] = x_all[(size_t)b * 8192 + (64 + l) * 64 + 63];
    asm volatile("s_waitcnt lgkmcnt(0)" ::: "memory");
    __builtin_amdgcn_sched_barrier(0);

#define LOADSET(R, T) do { \
        int _t = (T) <= 127 ? (T) : 127; \
        const u8* _p = npcl + ((size_t)(_t >> 4) << 18) + ((size_t)(_t & 15) << 14); \
        _Pragma("unroll") \
        for (int _k = 0; _k < 16; ++_k) \
            R[_k] = *reinterpret_cast<const uint4*>(_p + _k * 1024); \
    } while (0)

    uint4 nA[16], nB[16];
    LOADSET(nA, 1);          // issue early; tpc compute hides latency

    // tpc (exact f32): lane l -> n=l and n=64+l
    float a0 = 0.f, a1 = 0.f;
    #pragma unroll
    for (int t4 = 0; t4 < 16; ++t4) {
        float4 xv = *reinterpret_cast<const float4*>(x0_lds + t4 * 4);
        float4 w0 = *reinterpret_cast<const float4*>(tp + l * 64 + t4 * 4);
        float4 w1 = *reinterpret_cast<const float4*>(tp + (64 + l) * 64 + t4 * 4);
        a0 += sigf(w0.x) * xv.x; a0 += sigf(w0.y) * xv.y;
        a0 += sigf(w0.z) * xv.z; a0 += sigf(w0.w) * xv.w;
        a1 += sigf(w1.x) * xv.x; a1 += sigf(w1.y) * xv.y;
        a1 += sigf(w1.z) * xv.z; a1 += sigf(w1.w) * xv.w;
    }
    tpc_lds[l] = a0; tpc_lds[64 + l] = a1;
    float out_r = a0;                       // lane 0 holds tpc[0]
    asm volatile("s_waitcnt lgkmcnt(0)" ::: "memory");
    __builtin_amdgcn_sched_barrier(0);

    // step 1: cur1 = clip01(npc1 . tpc), tpc in f32 (unclipped range)
    {
        float s0f = 0.f, s1f = 0.f;
        #pragma unroll
        for (int k = 0; k < 8; ++k) {
            u32 ax[4] = {nA[k].x, nA[k].y, nA[k].z, nA[k].w};
            u32 bx[4] = {nA[k + 8].x, nA[k + 8].y, nA[k + 8].z, nA[k + 8].w};
            #pragma unroll
            for (int w = 0; w < 4; ++w) {
                float4 tv = *reinterpret_cast<const float4*>(tpc_lds + k * 16 + w * 4);
                u32 aw = ax[w], bw = bx[w];
                s0f += (float)(aw & 255u) * tv.x + (float)((aw >> 8) & 255u) * tv.y
                     + (float)((aw >> 16) & 255u) * tv.z + (float)(aw >> 24) * tv.w;
                s1f += (float)(bw & 255u) * tv.x + (float)((bw >> 8) & 255u) * tv.y
                     + (float)((bw >> 16) & 255u) * tv.z + (float)(bw >> 24) * tv.w;
            }
        }
        float c0 = clip01(s0f * (1.f / 255.f));
        float c1 = clip01(s1f * (1.f / 255.f));
        float mk = masks_lds[1];
        if (l == 0) out_r = out_r * mk + c0 * (1.f - mk);
        prev_lds[0][l]      = (u8)(c0 * 255.f + 0.5f);
        prev_lds[0][64 + l] = (u8)(c1 * 255.f + 0.5f);
        asm volatile("s_waitcnt lgkmcnt(0)" ::: "memory");
        __builtin_amdgcn_sched_barrier(0);
    }

    int p = 0;
    LOADSET(nA, 2); LOADSET(nB, 3);

#define STEP(R, S) do { \
        uint4 pv[8]; \
        _Pragma("unroll") \
        for (int _q = 0; _q < 8; ++_q) \
            pv[_q] = *reinterpret_cast<const uint4*>(&prev_lds[p][_q * 16]); \
        float mk = masks_lds[(S)]; \
        u32 s0 = 0, t0 = 0, s1 = 0, t1 = 0; \
        _Pragma("unroll") \
        for (int _k = 0; _k < 4; ++_k) { \
            s0 = ud4(R[_k].x, pv[_k].x, s0); s0 = ud4(R[_k].y, pv[_k].y, s0); \
            s0 = ud4(R[_k].z, pv[_k].z, s0); s0 = ud4(R[_k].w, pv[_k].w, s0); \
        } \
        _Pragma("unroll") \
        for (int _k = 4; _k < 8; ++_k) { \
            t0 = ud4(R[_k].x, pv[_k].x, t0); t0 = ud4(R[_k].y, pv[_k].y, t0); \
            t0 = ud4(R[_k].z, pv[_k].z, t0); t0 = ud4(R[_k].w, pv[_k].w, t0); \
        } \
        _Pragma("unroll") \
        for (int _k = 8; _k < 12; ++_k) { \
            s1 = ud4(R[_k].x, pv[_k - 8].x, s1); s1 = ud4(R[_k].y, pv[_k - 8].y, s1); \
            s1 = ud4(R[_k].z, pv[_k - 8].z, s1); s1 = ud4(R[_k].w, pv[_k - 8].w, s1); \
        } \
        _Pragma("unroll") \
        for (int _k = 12; _k < 16; ++_k) { \
            t1 = ud4(R[_k].x, pv[_k - 8].x, t1); t1 = ud4(R[_k].y, pv[_k - 8].y, t1); \
            t1 = ud4(R[_k].z, pv[_k - 8].z, t1); t1 = ud4(R[_k].w, pv[_k - 8].w, t1); \
        } \
        float c0 = fminf((float)(s0 + t0) * (1.f / 65025.f), 1.f); \
        float c1 = fminf((float)(s1 + t1) * (1.f / 65025.f), 1.f); \
        u32 q0 = (u32)(c0 * 255.f + 0.5f), q1 = (u32)(c1 * 255.f + 0.5f); \
        if (l == 0) out_r = out_r * mk + c0 * (1.f - mk); \
        prev_lds[p ^ 1][l]      = (u8)q0; \
        prev_lds[p ^ 1][64 + l] = (u8)q1; \
        asm volatile("s_waitcnt lgkmcnt(0)" ::: "memory"); \
        __builtin_amdgcn_sched_barrier(0); \
        p ^= 1; \
    } while (0)

    for (int g = 0; g < 63; ++g) {
        const int s = 2 + 2 * g;
        STEP(nA, s);     LOADSET(nA, s + 2);
        STEP(nB, s + 1); LOADSET(nB, s + 3);
    }
#undef STEP
#undef LOADSET

    if (l == 0) outp[b] = out_r;
}

// ---------------------------------------------------------------------------
// Fallback (known-passing round-2 kernel): fused recurrence, 2 MB ws.
__global__ __launch_bounds__(256) void sig_transpose(const float* __restrict__ ntp,
                                                     u32* __restrict__ out) {
    __shared__ float lds[64 * 65];
    const int nm0 = blockIdx.x * 64;
    const int tid = threadIdx.x;
    #pragma unroll
    for (int it = 0; it < 16; ++it) {
        int idx = it * 256 + tid;
        int r = idx >> 6, c = idx & 63;
        lds[r * 65 + c] = sigf(ntp[(nm0 + r) * 64 + c]);
    }
    __syncthreads();
    #pragma unroll
    for (int it = 0; it < 8; ++it) {
        int o = it * 256 + tid;
        int tpi = o >> 6, r = o & 63;
        f16x2 h;
        h[0] = (f16)lds[r * 65 + 2 * tpi];
        h[1] = (f16)lds[r * 65 + 2 * tpi + 1];
        out[tpi * NM + nm0 + r] = __builtin_bit_cast(u32, h);
    }
}

__global__ __launch_bounds__(1024) void grammar_fused(
    const float* __restrict__ x_all,
    const float* __restrict__ tp,
    const u32*  __restrict__ ntpT2,
    float* __restrict__ outp) {
    __shared__ float x_lds[LL * TT];
    __shared__ float prevbuf[2][NN];
    __shared__ u32 x2_lds[2][32];

    const int b = blockIdx.x;
    const int tid = threadIdx.x;
    const int lane16 = tid & 15;
    const int g = tid >> 4;
    const int mbase = lane16 * 8;

    const float* xb = x_all + b * (LL * TT);
    #pragma unroll
    for (int it = 0; it < 8; ++it) {
        int idx = it * 1024 + tid;
        x_lds[idx] = xb[idx];
    }
    __syncthreads();

    if (tid < NN) {
        float acc = 0.f;
        #pragma unroll 8
        for (int t = 0; t < TT; ++t)
            acc += sigf(tp[tid * TT + t]) * x_lds[t];
        prevbuf[0][tid] = acc;
    }
    __syncthreads();
    float out_r = 0.f;
    if (tid == 0) out_r = prevbuf[0][0];

    int p = 0;
    for (int i0 = 1; i0 < LL; i0 += 2) {
        const int ns = (LL - i0) >= 2 ? 2 : 1;
        if (tid < 64) {
            int s = tid >> 5, tpi = tid & 31;
            f16x2 h;
            if (s < ns) {
                h[0] = (f16)x_lds[(i0 + s) * TT + 2 * tpi];
                h[1] = (f16)x_lds[(i0 + s) * TT + 2 * tpi + 1];
            } else {
                h[0] = (f16)0.f; h[1] = (f16)0.f;
            }
            x2_lds[s][tpi] = __builtin_bit_cast(u32, h);
        }
        __syncthreads();

        float acc[2][2][8];
        #pragma unroll
        for (int k = 0; k < 2; ++k)
            #pragma unroll
            for (int s = 0; s < 2; ++s)
                #pragma unroll
                for (int j = 0; j < 8; ++j) acc[k][s][j] = 0.f;

        #pragma unroll 2
        for (int tpi = 0; tpi < 32; ++tpi) {
            f16x2 xv0 = __builtin_bit_cast(f16x2, x2_lds[0][tpi]);
            f16x2 xv1 = __builtin_bit_cast(f16x2, x2_lds[1][tpi]);
            const u32* base = ntpT2 + tpi * NM + 8 * tid;
            #pragma unroll
            for (int k = 0; k < 2; ++k) {
                uint4 w0 = *reinterpret_cast<const uint4*>(base + 8192 * k);
                uint4 w1 = *reinterpret_cast<const uint4*>(base + 8192 * k + 4);
                u32 wv[8] = {w0.x, w0.y, w0.z, w0.w, w1.x, w1.y, w1.z, w1.w};
                #pragma unroll
                for (int j = 0; j < 8; ++j) {
                    f16x2 w = __builtin_bit_cast(f16x2, wv[j]);
                    acc[k][0][j] = fdot2f(w, xv0, acc[k][0][j]);
                    acc[k][1][j] = fdot2f(w, xv1, acc[k][1][j]);
                }
            }
        }

        for (int s = 0; s < ns; ++s) {
            float4 pv0 = *reinterpret_cast<const float4*>(&prevbuf[p][mbase]);
            float4 pv1 = *reinterpret_cast<const float4*>(&prevbuf[p][mbase + 4]);
            float pvv[8] = {pv0.x, pv0.y, pv0.z, pv0.w, pv1.x, pv1.y, pv1.z, pv1.w};
            #pragma unroll
            for (int k = 0; k < 2; ++k) {
                float part = 0.f;
                #pragma unroll
                for (int j = 0; j < 8; ++j) {
                    float npcv = clip01(acc[k][s][j]);
                    part += npcv * pvv[j];
                }
                part += __shfl_xor(part, 1);
                part += __shfl_xor(part, 2);
                part += __shfl_xor(part, 4);
                part += __shfl_xor(part, 8);
                if (lane16 == 0) {
                    float c = clip01(part);
                    prevbuf[p ^ 1][g + 64 * k] = c;
                    if (tid == 0 && k == 0) {
                        float mask = x_lds[(i0 + s) * TT + 63];
                        out_r = out_r * mask + c * (1.f - mask);
                    }
                }
            }
            p ^= 1;
            __syncthreads();
        }
    }

    if (tid == 0) outp[b] = out_r;
}

// ---------------------------------------------------------------------------
extern "C" void kernel_launch(void* const* d_in, const int* in_sizes, int n_in,
                              void* d_out, int out_size, void* d_ws, size_t ws_size,
                              hipStream_t stream) {
    const float* input_tensor = (const float*)d_in[0];   // [64][128][64]
    const float* term_prod    = (const float*)d_in[1];   // [128][64]
    const float* nonterm_prod = (const float*)d_in[2];   // [128][128][64]
    float* outp = (float*)d_out;                         // [64]

    const size_t MB = 1024 * 1024;
    const size_t NPC_BYTES = 128 * MB;   // layout R
    const size_t WPK_BYTES = 2 * MB;     // bf16 A-frags
    const size_t XPK_BYTES = 1 * MB;     // bf16 B-frags

    if (ws_size >= NPC_BYTES + WPK_BYTES + XPK_BYTES + MB) {
        u8* npcbuf  = (u8*)d_ws;
        ushort* wpk = (ushort*)((char*)d_ws + NPC_BYTES);
        ushort* xpk = (ushort*)((char*)d_ws + NPC_BYTES + WPK_BYTES);
        pack_w<<<512, 256, 0, stream>>>(nonterm_prod, wpk);
        pack_x<<<256, 256, 0, stream>>>(input_tensor, xpk);
        gemm_mfma<<<1024, 256, 0, stream>>>(wpk, xpk, npcbuf);
        recur4<<<BB, 64, 0, stream>>>(input_tensor, term_prod, npcbuf, outp);
    } else {
        u32* ntpT2 = (u32*)d_ws;
        sig_transpose<<<256, 256, 0, stream>>>(nonterm_prod, ntpT2);
        grammar_fused<<<BB, 1024, 0, stream>>>(input_tensor, term_prod, ntpT2, outp);
    }
}